// Round 2
// baseline (125646.643 us; speedup 1.0000x reference)
//
#include <hip/hip_runtime.h>
#include <stdint.h>

// Problem constants (B,S,I,H,O) = (64, 2048, 256, 512, 256), all fp32.
#define Bn 64
#define Sn 2048
#define In 256
#define Hn 512
#define On 256
#define KS 384   // front-chain length (thread A); back = Hn - KS = 128 (thread B)

// ---------------------------------------------------------------------------
// BIT-EXACT constraint (proven, absmax 0.0): per output element the
// arithmetic must be exactly
//   xacc = fma-chain_{i=0..255 asc}(xs[i], Wxh[i][j]);  xw = xacc + bias_h[j]
//   hacc = fma-chain_{k=0..511 asc}(hs[k], Whh[k][j]);  u  = xw + hacc
//   h' = xla_tanh(u);   y = fma-chain_k(h[k],Why[k][o]) + bias_y[o]
// All chains below are byte-identical to the verified version.
//
// SYNC PROTOCOL v3 (this round). v2 (per-lane tagged-word polling) was
// correct but congested the coherence point: agent-scope polls bypass
// L1/L2 (per-XCD L2 non-coherent), so each poll round was 128 lanes x 8B
// SEPARATE fabric transactions x 256 blocks, continuously -> FETCH_SIZE
// 13.9 GB, publish stores queued behind polls, 60us/step. Fix:
//   * payload stays as self-validating tagged u64 words
//     (tag=step<<32 | f32 bits) -> still no fences / no vmcnt-drain barrier
//   * NEW compact ready-tag word rtag[b][slice][parity] (64B-strided):
//     publisher stores it (one thread) after issuing its payload stores;
//     consumers SPIN ON THIS ONE BROADCAST WORD (1 coalesced transaction
//     per wave per slice per round, self-paced by dependent-load RTT +
//     s_sleep(1)), then read the 128 payload words ONCE and per-lane
//     validate tags (micro-spin only on the rare straggler store).
//   -> ~100x fewer poll transactions; publish->consume = ~3 MALL RTTs.
// No memset needed: 0xAA workspace poison decodes to negative tags.
// Slot overwrite safety (parity double-buffer) is transitive, proven:
// publish(t+1) <= staged all remote t <= peers published t <= peers'
// t-1 reads retired (reads complete before barrier #0, publish after #1).
// Partition unchanged (proven resident): 256 blocks = 64 batches x 4
// column-slices; 256 threads = 128 A (384 Whh regs, chain k<384) +
// 128 B (256 Wxh + 128 Whh regs, xacc + chain k>=384 + tanh + publish).
// ~420 regs/thread -> 1 wave/SIMD -> 1 block/CU, all 256 co-resident.
// ---------------------------------------------------------------------------
typedef unsigned long long u64;

__device__ __forceinline__ float xla_tanh(float x) {
    const float ax = __builtin_fabsf(x);
    float xc = fmaxf(-7.99881172180175781f, fminf(7.99881172180175781f, x));
    const float x2 = xc * xc;
    float p = fmaf(x2, -2.76076847742355e-16f, 2.00018790482477e-13f);
    p = fmaf(x2, p, -8.60467152213735e-11f);
    p = fmaf(x2, p, 5.12229709037114e-08f);
    p = fmaf(x2, p, 1.48572235717979e-05f);
    p = fmaf(x2, p, 6.37261928875436e-04f);
    p = fmaf(x2, p, 4.89352455891786e-03f);
    p = xc * p;
    float q = fmaf(x2, 1.19825839466702e-06f, 1.18534705686654e-04f);
    q = fmaf(x2, q, 2.26843463243900e-03f);
    q = fmaf(x2, q, 4.89352518554385e-03f);
    return ax < 0.0004f ? x : p / q;
}

__device__ __forceinline__ u64 pub_ld(const u64* p) {
    return __hip_atomic_load(p, __ATOMIC_RELAXED, __HIP_MEMORY_SCOPE_AGENT);
}
__device__ __forceinline__ void pub_st(u64* p, u64 v) {
    __hip_atomic_store(p, v, __ATOMIC_RELAXED, __HIP_MEMORY_SCOPE_AGENT);
}
__device__ __forceinline__ int tag_ld(const int* p) {
    return __hip_atomic_load(p, __ATOMIC_RELAXED, __HIP_MEMORY_SCOPE_AGENT);
}
__device__ __forceinline__ void tag_st(int* p, int v) {
    __hip_atomic_store(p, v, __ATOMIC_RELAXED, __HIP_MEMORY_SCOPE_AGENT);
}
__device__ __forceinline__ int pub_tag(u64 w) { return (int)(unsigned)(w >> 32); }
__device__ __forceinline__ float pub_val(u64 w) { return __uint_as_float((unsigned)w); }
__device__ __forceinline__ u64 pub_pack(float v, int t) {
    return ((u64)(unsigned)t << 32) | (u64)__float_as_uint(v);
}

__global__ __launch_bounds__(256, 1) void rnn_scan(const float* __restrict__ x,
                                                   const float* __restrict__ Wxh,
                                                   const float* __restrict__ Whh,
                                                   const float* __restrict__ bias_h,
                                                   u64* __restrict__ hpub,
                                                   int* __restrict__ rtag,
                                                   float* __restrict__ hlast) {
    const int blk = blockIdx.x;
    const int b = blk & 63;          // batch
    const int s = blk >> 6;          // column-slice 0..3
    const int tid = threadIdx.x;
    const int c = tid & 127;         // column within slice
    const bool isA = tid < 128;      // wave-uniform role split (waves 0,1 = A; 2,3 = B)
    const int j = s * 128 + c;       // global column

    __shared__ float hs[2][Hn];      // double-buffered h (read t&1, write 1-(t&1))
    __shared__ float xs[2][In];      // double-buffered x row
    __shared__ float pacc[128];      // A->B chain-accumulator handoff

    // Weight registers (384 floats/thread, coalesced loads: lanes = consecutive j)
    float W0[KS];
    if (isA) {
#pragma unroll
        for (int k = 0; k < KS; ++k) W0[k] = Whh[(size_t)k * Hn + j];
    } else {
#pragma unroll
        for (int i = 0; i < In; ++i) W0[i] = Wxh[(size_t)i * Hn + j];
#pragma unroll
        for (int k = 0; k < 128; ++k) W0[In + k] = Whh[(size_t)(KS + k) * Hn + j];
    }
    const float bh = isA ? 0.f : bias_h[j];

    hs[0][tid] = 0.f;                          // h_0 = 0
    hs[0][tid + 256] = 0.f;
    xs[0][tid] = x[(size_t)b * Sn * In + tid]; // row 0 (256 threads = full row)
    __syncthreads();

    // Tagged publish slots: [batch][slice][parity][128 cols], u64 each.
    u64* const bpub = hpub + (size_t)b * 4 * 2 * 128;
    u64* const mypub = bpub + (size_t)s * 256;
    // Compact ready tags: [batch][slice] on separate 64B lines, word [parity].
    int* const myrtag = rtag + (b * 4 + s) * 16;

    float hn = 0.f;

    for (int t = 0; t < Sn; ++t) {
        const int rp = t & 1;
        float xw_ = 0.f;

        if (isA) {
            // ---- stage remote h_t for slices 0,1,2 (A's chain range) ----
            if (t > 0) {
                const bool n0 = (s != 0), n1 = (s != 1), n2 = (s != 2);
                const int* f0 = rtag + (b * 4 + 0) * 16 + rp;
                const int* f1 = rtag + (b * 4 + 1) * 16 + rp;
                const int* f2 = rtag + (b * 4 + 2) * 16 + rp;
                // Spin on broadcast ready-tags: 1 coalesced txn/wave/slice/round,
                // self-paced by dependent-load RTT + s_sleep.
                int t0 = n0 ? tag_ld(f0) : t;
                int t1 = n1 ? tag_ld(f1) : t;
                int t2 = n2 ? tag_ld(f2) : t;
                while (t0 < t || t1 < t || t2 < t) {
                    __builtin_amdgcn_s_sleep(1);
                    if (t0 < t) t0 = tag_ld(f0);
                    if (t1 < t) t1 = tag_ld(f1);
                    if (t2 < t) t2 = tag_ld(f2);
                }
                // Payload: read once (back-to-back, latencies overlap),
                // per-lane tag validation catches straggler stores.
                const u64* p0 = bpub + 0 * 256 + rp * 128 + c;
                const u64* p1 = bpub + 1 * 256 + rp * 128 + c;
                const u64* p2 = bpub + 2 * 256 + rp * 128 + c;
                u64 v0 = 0, v1 = 0, v2 = 0;
                if (n0) v0 = pub_ld(p0);
                if (n1) v1 = pub_ld(p1);
                if (n2) v2 = pub_ld(p2);
                if (n0) { while (pub_tag(v0) < t) v0 = pub_ld(p0); hs[rp][c]       = pub_val(v0); }
                if (n1) { while (pub_tag(v1) < t) v1 = pub_ld(p1); hs[rp][128 + c] = pub_val(v1); }
                if (n2) { while (pub_tag(v2) < t) v2 = pub_ld(p2); hs[rp][256 + c] = pub_val(v2); }
            }
        } else {
            // prefetch next x row (2 elems/thread), issued first to hide latency
            float xn0 = 0.f, xn1 = 0.f;
            if (t + 1 < Sn) {
                xn0 = x[((size_t)b * Sn + t + 1) * In + c];
                xn1 = x[((size_t)b * Sn + t + 1) * In + 128 + c];
            }
            // one-shot ready-tag read issued BEFORE xacc: the 1024cy xacc
            // chain hides the first poll RTT
            const bool need3 = (t > 0) && (s != 3);
            const int* f3 = rtag + (b * 4 + 3) * 16 + rp;
            int t3 = need3 ? tag_ld(f3) : 0;

            // xacc: i = 0..255, ascending (exact verified order)
            float xa = 0.f;
            const float4* x4 = (const float4*)&xs[rp][0];
#pragma unroll
            for (int q = 0; q < In / 4; ++q) {
                float4 xv = x4[q];
                xa = fmaf(xv.x, W0[4 * q + 0], xa);
                xa = fmaf(xv.y, W0[4 * q + 1], xa);
                xa = fmaf(xv.z, W0[4 * q + 2], xa);
                xa = fmaf(xv.w, W0[4 * q + 3], xa);
            }
            xw_ = xa + bh;

            if (need3) {
                while (t3 < t) { __builtin_amdgcn_s_sleep(1); t3 = tag_ld(f3); }
                const u64* p3 = bpub + 3 * 256 + rp * 128 + c;
                u64 v3 = pub_ld(p3);
                while (pub_tag(v3) < t) v3 = pub_ld(p3);
                hs[rp][KS + c] = pub_val(v3);   // slice 3 (B's chain range)
            }
            if (t + 1 < Sn) {
                xs[1 - rp][c] = xn0;
                xs[1 - rp][128 + c] = xn1;
            }
        }
        __syncthreads();   // #0: hs[rp] complete (remote staged, local from t-1)

        if (isA) {
            // hacc prefix: k = 0..383, ascending, single accumulator (exact order)
            float acc = 0.f;
            const float4* h4 = (const float4*)&hs[rp][0];
#pragma unroll
            for (int q = 0; q < KS / 4; ++q) {
                float4 hv = h4[q];   // broadcast ds_read_b128
                acc = fmaf(hv.x, W0[4 * q + 0], acc);
                acc = fmaf(hv.y, W0[4 * q + 1], acc);
                acc = fmaf(hv.z, W0[4 * q + 2], acc);
                acc = fmaf(hv.w, W0[4 * q + 3], acc);
            }
            pacc[c] = acc;
        }
        __syncthreads();   // #1: pacc ready

        if (!isA) {
            // hacc suffix: k = 384..511, continuing the SAME chain
            float acc = pacc[c];
            const float4* h4 = (const float4*)&hs[rp][KS];
#pragma unroll
            for (int q = 0; q < 32; ++q) {
                float4 hv = h4[q];
                acc = fmaf(hv.x, W0[In + 4 * q + 0], acc);
                acc = fmaf(hv.y, W0[In + 4 * q + 1], acc);
                acc = fmaf(hv.z, W0[In + 4 * q + 2], acc);
                acc = fmaf(hv.w, W0[In + 4 * q + 3], acc);
            }
            const float u = xw_ + acc;        // exact association
            hn = xla_tanh(u);
            hs[1 - rp][j] = hn;               // local slice for step t+1
            if (t + 1 < Sn) {
                // tagged payload publish (no fence needed: self-validating)
                pub_st(mypub + (size_t)(1 - rp) * 128 + c, pub_pack(hn, t + 1));
                // compact ready-tag: single store, issued after this wave's
                // payload store; wave-3 stragglers are caught by per-lane
                // payload validation at the consumer
                if (tid == 128) tag_st(myrtag + (1 - rp), t + 1);
            }
        }
        // no third barrier: publish visibility is carried by the tags,
        // LDS hazards for step t+1 are covered by #0/#1
    }

    if (!isA) hlast[(size_t)b * Hn + j] = hn;
}

// ---------------------------------------------------------------------------
// y[b][o] = fma-chain_k(h_last[b][k]*Why[k][o]) + bias_y[o]  (unchanged, exact)
// ---------------------------------------------------------------------------
__global__ __launch_bounds__(256) void out_gemm(const float* __restrict__ hlast,
                                                const float* __restrict__ Why,
                                                const float* __restrict__ bias_y,
                                                float* __restrict__ y) {
    const int b = blockIdx.x, o = threadIdx.x;
    __shared__ float hs[Hn];
    hs[o] = hlast[(size_t)b * Hn + o];
    hs[o + 256] = hlast[(size_t)b * Hn + o + 256];
    __syncthreads();
    float acc = 0.0f;
#pragma unroll 8
    for (int k = 0; k < Hn; ++k)
        acc = fmaf(hs[k], Why[(size_t)k * On + o], acc);
    y[(size_t)b * On + o] = acc + bias_y[o];
}

// ---------------------------------------------------------------------------
extern "C" void kernel_launch(void* const* d_in, const int* in_sizes, int n_in,
                              void* d_out, int out_size, void* d_ws, size_t ws_size,
                              hipStream_t stream) {
    // Map inputs by size (x=33554432, Whh=262144, Wxh/Why=131072 in order,
    // bias_h=512, bias_y=256).
    const float *x = nullptr, *Wxh = nullptr, *Whh = nullptr, *Why = nullptr,
                *bias_h = nullptr, *bias_y = nullptr;
    for (int i = 0; i < n_in; ++i) {
        const float* p = (const float*)d_in[i];
        const int sz = in_sizes[i];
        if (sz == Bn * Sn * In) x = p;
        else if (sz == Hn * Hn) Whh = p;
        else if (sz == In * Hn) { if (!Wxh) Wxh = p; else Why = p; }
        else if (sz == Hn) bias_h = p;
        else if (sz == On) bias_y = p;
    }
    float* y = (float*)d_out;

    // workspace: tagged hpub (64*4*2*128 u64 = 512 KB) + rtag (16 KB) +
    // hlast (128 KB). NO memset: 0xAA poison decodes to negative tags,
    // which never satisfy tag >= t for t >= 1.
    char* ws = (char*)d_ws;
    u64* hpub = (u64*)ws;
    size_t hpub_bytes = (size_t)Bn * 4 * 2 * 128 * sizeof(u64);
    int* rtag = (int*)(ws + hpub_bytes);
    size_t rtag_bytes = (size_t)Bn * 4 * 16 * sizeof(int);
    float* hlast = (float*)(ws + hpub_bytes + rtag_bytes);

    rnn_scan<<<dim3(256), dim3(256), 0, stream>>>(x, Wxh, Whh, bias_h,
                                                  hpub, rtag, hlast);
    out_gemm<<<dim3(Bn), dim3(On), 0, stream>>>(hlast, Why, bias_y, y);
}

// Round 3
// 124161.475 us; speedup vs baseline: 1.0120x; 1.0120x over previous
//
#include <hip/hip_runtime.h>
#include <stdint.h>

// Problem constants (B,S,I,H,O) = (64, 2048, 256, 512, 256), all fp32.
#define Bn 64
#define Sn 2048
#define In 256
#define Hn 512
#define On 256
#define KS 384   // front-chain length (thread A); back = Hn - KS = 128 (thread B)

// ---------------------------------------------------------------------------
// BIT-EXACT constraint (proven, absmax 0.0): per output element the
// arithmetic must be exactly
//   xacc = fma-chain_{i=0..255 asc}(xs[i], Wxh[i][j]);  xw = xacc + bias_h[j]
//   hacc = fma-chain_{k=0..511 asc}(hs[k], Whh[k][j]);  u  = xw + hacc
//   h' = xla_tanh(u);   y = fma-chain_k(h[k],Why[k][o]) + bias_y[o]
// All chains below are byte-identical to the verified versions.
//
// SYNC PROTOCOL v4. History:
//  v0 (33.7ms): publish + vmcnt-drain barrier + release flag + acquire spins.
//  v2/v3 (~125ms): tagged words removed the fences BUT per-wave/per-lane
//    unpaced agent-scope spins offered ~10G coherent req/s to the MALL
//    (FETCH 14-18 GB); publish stores queued ~60us behind polls.
// v4 keeps the tagged-payload semantics (self-validating u64 =
// step<<32 | f32 bits; no fences, no drain, no memset — 0xAA poison = neg
// tag) and crushes the poll population:
//   * ONE poller per block: wave0, lane0-masked loads + shfl broadcast,
//     polls 2 sentinel payload words per needed slice (cols 0 & 64 = one
//     per publisher wave), s_sleep(8)-paced -> <=6 req / ~0.5us / BLOCK.
//   * Poller fans readiness out through LDS flags; other waves spin on
//     LDS (free), then read payload ONCE + per-lane validate (paced
//     fallback, expected never taken).
//   * B issues its slice-3 payload read speculatively BEFORE the 1024cy
//     xacc chain; if fresh, staging RTT fully hidden.
// Slot overwrite safety (parity double-buffer) transitive as before:
// publish(t+1) <= staged all remote t <= peers published t <= peers'
// t-1 reads retired (reads pre-barrier#0, publish post-barrier#1).
// Partition unchanged (proven resident): 256 blocks = 64 batches x 4
// column-slices; 256 threads = 128 A (384 Whh regs, chain k<384) +
// 128 B (256 Wxh + 128 Whh regs, xacc + chain k>=384 + tanh + publish).
// ---------------------------------------------------------------------------
typedef unsigned long long u64;

__device__ __forceinline__ float xla_tanh(float x) {
    const float ax = __builtin_fabsf(x);
    float xc = fmaxf(-7.99881172180175781f, fminf(7.99881172180175781f, x));
    const float x2 = xc * xc;
    float p = fmaf(x2, -2.76076847742355e-16f, 2.00018790482477e-13f);
    p = fmaf(x2, p, -8.60467152213735e-11f);
    p = fmaf(x2, p, 5.12229709037114e-08f);
    p = fmaf(x2, p, 1.48572235717979e-05f);
    p = fmaf(x2, p, 6.37261928875436e-04f);
    p = fmaf(x2, p, 4.89352455891786e-03f);
    p = xc * p;
    float q = fmaf(x2, 1.19825839466702e-06f, 1.18534705686654e-04f);
    q = fmaf(x2, q, 2.26843463243900e-03f);
    q = fmaf(x2, q, 4.89352518554385e-03f);
    return ax < 0.0004f ? x : p / q;
}

__device__ __forceinline__ u64 pub_ld(const u64* p) {
    return __hip_atomic_load(p, __ATOMIC_RELAXED, __HIP_MEMORY_SCOPE_AGENT);
}
__device__ __forceinline__ void pub_st(u64* p, u64 v) {
    __hip_atomic_store(p, v, __ATOMIC_RELAXED, __HIP_MEMORY_SCOPE_AGENT);
}
__device__ __forceinline__ int lds_ld(const int* p) {
    return __hip_atomic_load(p, __ATOMIC_RELAXED, __HIP_MEMORY_SCOPE_WORKGROUP);
}
__device__ __forceinline__ void lds_st(int* p, int v) {
    __hip_atomic_store(p, v, __ATOMIC_RELAXED, __HIP_MEMORY_SCOPE_WORKGROUP);
}
__device__ __forceinline__ int pub_tag(u64 w) { return (int)(unsigned)(w >> 32); }
__device__ __forceinline__ float pub_val(u64 w) { return __uint_as_float((unsigned)w); }
__device__ __forceinline__ u64 pub_pack(float v, int t) {
    return ((u64)(unsigned)t << 32) | (u64)__float_as_uint(v);
}
__device__ __forceinline__ u64 bcast0(u64 v) {
    return (u64)__shfl((long long)v, 0, 64);   // lane-0 broadcast within wave
}

__global__ __launch_bounds__(256, 1) void rnn_scan(const float* __restrict__ x,
                                                   const float* __restrict__ Wxh,
                                                   const float* __restrict__ Whh,
                                                   const float* __restrict__ bias_h,
                                                   u64* __restrict__ hpub,
                                                   float* __restrict__ hlast) {
    const int blk = blockIdx.x;
    const int b = blk & 63;          // batch
    const int s = blk >> 6;          // column-slice 0..3
    const int tid = threadIdx.x;
    const int c = tid & 127;         // column within slice
    const int lane = tid & 63;
    const bool isA = tid < 128;      // wave-uniform role split
    const int j = s * 128 + c;       // global column

    __shared__ float hs[2][Hn];      // double-buffered h (read t&1, write 1-(t&1))
    __shared__ float xs[2][In];      // double-buffered x row
    __shared__ float pacc[128];      // A->B chain-accumulator handoff
    __shared__ int lready[2][4];     // poller -> consumers: slice ready tags

    // The three remote slices this block needs = {0,1,2,3} \ {s}, ascending.
    const int r0 = (s == 0) ? 1 : 0;
    const int r1 = (s <= 1) ? 2 : 1;
    const int r2 = (s <= 2) ? 3 : 2;

    // Weight registers (384 floats/thread, coalesced loads: lanes = consecutive j)
    float W0[KS];
    if (isA) {
#pragma unroll
        for (int k = 0; k < KS; ++k) W0[k] = Whh[(size_t)k * Hn + j];
    } else {
#pragma unroll
        for (int i = 0; i < In; ++i) W0[i] = Wxh[(size_t)i * Hn + j];
#pragma unroll
        for (int k = 0; k < 128; ++k) W0[In + k] = Whh[(size_t)(KS + k) * Hn + j];
    }
    const float bh = isA ? 0.f : bias_h[j];

    hs[0][tid] = 0.f;                          // h_0 = 0
    hs[0][tid + 256] = 0.f;
    xs[0][tid] = x[(size_t)b * Sn * In + tid]; // row 0 (256 threads = full row)
    if (tid < 8) ((int*)lready)[tid] = 0;
    __syncthreads();

    // Tagged publish slots: [batch][slice][parity][128 cols], u64 each.
    u64* const bpub = hpub + (size_t)b * 4 * 2 * 128;
    u64* const mypub = bpub + (size_t)s * 256;

    float hn = 0.f;

    for (int t = 0; t < Sn; ++t) {
        const int rp = t & 1;
        float xw_ = 0.f;

        if (isA) {
            if (t > 0) {
                if (tid < 64) {
                    // ---- wave0 = the block's single fabric poller ----
                    // 2 sentinels per needed slice (cols 0 & 64: one per
                    // publisher wave). lane0-masked loads, shfl broadcast,
                    // wave-uniform loop, s_sleep(8) pacing.
                    const u64* a0 = bpub + r0 * 256 + rp * 128;
                    const u64* a1 = bpub + r1 * 256 + rp * 128;
                    const u64* a2 = bpub + r2 * 256 + rp * 128;
                    u64 x00 = 0, x01 = 0, x10 = 0, x11 = 0, x20 = 0, x21 = 0;
                    if (lane == 0) {
                        x00 = pub_ld(a0); x01 = pub_ld(a0 + 64);
                        x10 = pub_ld(a1); x11 = pub_ld(a1 + 64);
                        x20 = pub_ld(a2); x21 = pub_ld(a2 + 64);
                    }
                    x00 = bcast0(x00); x01 = bcast0(x01);
                    x10 = bcast0(x10); x11 = bcast0(x11);
                    x20 = bcast0(x20); x21 = bcast0(x21);
                    bool d0 = false, d1 = false, d2 = false;
                    for (;;) {
                        if (!d0 && pub_tag(x00) >= t && pub_tag(x01) >= t) {
                            d0 = true; if (lane == 0) lds_st(&lready[rp][r0], t);
                        }
                        if (!d1 && pub_tag(x10) >= t && pub_tag(x11) >= t) {
                            d1 = true; if (lane == 0) lds_st(&lready[rp][r1], t);
                        }
                        if (!d2 && pub_tag(x20) >= t && pub_tag(x21) >= t) {
                            d2 = true; if (lane == 0) lds_st(&lready[rp][r2], t);
                        }
                        if (d0 && d1 && d2) break;
                        __builtin_amdgcn_s_sleep(8);
                        if (lane == 0) {
                            if (!d0) { x00 = pub_ld(a0); x01 = pub_ld(a0 + 64); }
                            if (!d1) { x10 = pub_ld(a1); x11 = pub_ld(a1 + 64); }
                            if (!d2) { x20 = pub_ld(a2); x21 = pub_ld(a2 + 64); }
                        }
                        if (!d0) { x00 = bcast0(x00); x01 = bcast0(x01); }
                        if (!d1) { x10 = bcast0(x10); x11 = bcast0(x11); }
                        if (!d2) { x20 = bcast0(x20); x21 = bcast0(x21); }
                    }
                } else {
                    // wave1: free LDS spin on the A-needed slice flags
                    const bool na0 = (s != 0), na1 = (s != 1), na2 = (s != 2);
                    while ((na0 && lds_ld(&lready[rp][0]) < t) ||
                           (na1 && lds_ld(&lready[rp][1]) < t) ||
                           (na2 && lds_ld(&lready[rp][2]) < t))
                        __builtin_amdgcn_s_sleep(1);
                }
                // ---- A staging: read payloads once, validate, LDS-write ----
                const bool na0 = (s != 0), na1 = (s != 1), na2 = (s != 2);
                const u64* p0 = bpub + 0 * 256 + rp * 128 + c;
                const u64* p1 = bpub + 1 * 256 + rp * 128 + c;
                const u64* p2 = bpub + 2 * 256 + rp * 128 + c;
                u64 v0 = 0, v1 = 0, v2 = 0;
                if (na0) v0 = pub_ld(p0);     // back-to-back: latencies overlap
                if (na1) v1 = pub_ld(p1);
                if (na2) v2 = pub_ld(p2);
                if (na0) {
                    while (pub_tag(v0) < t) { __builtin_amdgcn_s_sleep(2); v0 = pub_ld(p0); }
                    hs[rp][c] = pub_val(v0);
                }
                if (na1) {
                    while (pub_tag(v1) < t) { __builtin_amdgcn_s_sleep(2); v1 = pub_ld(p1); }
                    hs[rp][128 + c] = pub_val(v1);
                }
                if (na2) {
                    while (pub_tag(v2) < t) { __builtin_amdgcn_s_sleep(2); v2 = pub_ld(p2); }
                    hs[rp][256 + c] = pub_val(v2);
                }
            }
        } else {
            // prefetch next x row (2 elems/thread), issued first to hide latency
            float xn0 = 0.f, xn1 = 0.f;
            if (t + 1 < Sn) {
                xn0 = x[((size_t)b * Sn + t + 1) * In + c];
                xn1 = x[((size_t)b * Sn + t + 1) * In + 128 + c];
            }
            // speculative slice-3 payload read issued BEFORE xacc: the 1024cy
            // chain hides the RTT; validated (and if stale, properly waited
            // via the LDS flag) afterwards
            const bool need3 = (t > 0) && (s != 3);
            const u64* p3 = bpub + 3 * 256 + rp * 128 + c;
            u64 v3 = 0;
            if (need3) v3 = pub_ld(p3);

            // xacc: i = 0..255, ascending (exact verified order)
            float xa = 0.f;
            const float4* x4 = (const float4*)&xs[rp][0];
#pragma unroll
            for (int q = 0; q < In / 4; ++q) {
                float4 xv = x4[q];
                xa = fmaf(xv.x, W0[4 * q + 0], xa);
                xa = fmaf(xv.y, W0[4 * q + 1], xa);
                xa = fmaf(xv.z, W0[4 * q + 2], xa);
                xa = fmaf(xv.w, W0[4 * q + 3], xa);
            }
            xw_ = xa + bh;

            if (need3) {
                if (pub_tag(v3) < t) {
                    // speculation failed: wait on the poller's LDS flag (free),
                    // then one fresh read + paced per-lane validation
                    while (lds_ld(&lready[rp][3]) < t) __builtin_amdgcn_s_sleep(1);
                    v3 = pub_ld(p3);
                    while (pub_tag(v3) < t) { __builtin_amdgcn_s_sleep(2); v3 = pub_ld(p3); }
                }
                hs[rp][KS + c] = pub_val(v3);   // slice 3 (B's chain range)
            }
            if (t + 1 < Sn) {
                xs[1 - rp][c] = xn0;
                xs[1 - rp][128 + c] = xn1;
            }
        }
        __syncthreads();   // #0: hs[rp] complete (remote staged, local from t-1)

        if (isA) {
            // hacc prefix: k = 0..383, ascending, single accumulator (exact order)
            float acc = 0.f;
            const float4* h4 = (const float4*)&hs[rp][0];
#pragma unroll
            for (int q = 0; q < KS / 4; ++q) {
                float4 hv = h4[q];   // broadcast ds_read_b128
                acc = fmaf(hv.x, W0[4 * q + 0], acc);
                acc = fmaf(hv.y, W0[4 * q + 1], acc);
                acc = fmaf(hv.z, W0[4 * q + 2], acc);
                acc = fmaf(hv.w, W0[4 * q + 3], acc);
            }
            pacc[c] = acc;
        }
        __syncthreads();   // #1: pacc ready

        if (!isA) {
            // hacc suffix: k = 384..511, continuing the SAME chain
            float acc = pacc[c];
            const float4* h4 = (const float4*)&hs[rp][KS];
#pragma unroll
            for (int q = 0; q < 32; ++q) {
                float4 hv = h4[q];
                acc = fmaf(hv.x, W0[In + 4 * q + 0], acc);
                acc = fmaf(hv.y, W0[In + 4 * q + 1], acc);
                acc = fmaf(hv.z, W0[In + 4 * q + 2], acc);
                acc = fmaf(hv.w, W0[In + 4 * q + 3], acc);
            }
            const float u = xw_ + acc;        // exact association
            hn = xla_tanh(u);
            hs[1 - rp][j] = hn;               // local slice for step t+1
            // tagged publish: tag travels WITH the value; no fence, no drain,
            // no flag. Consumers validate per-word.
            if (t + 1 < Sn)
                pub_st(mypub + (size_t)(1 - rp) * 128 + c, pub_pack(hn, t + 1));
        }
        // no third barrier: LDS hazards for t+1 are covered by #0/#1
    }

    if (!isA) hlast[(size_t)b * Hn + j] = hn;
}

// ---------------------------------------------------------------------------
// y[b][o] = fma-chain_k(h_last[b][k]*Why[k][o]) + bias_y[o]  (unchanged, exact)
// ---------------------------------------------------------------------------
__global__ __launch_bounds__(256) void out_gemm(const float* __restrict__ hlast,
                                                const float* __restrict__ Why,
                                                const float* __restrict__ bias_y,
                                                float* __restrict__ y) {
    const int b = blockIdx.x, o = threadIdx.x;
    __shared__ float hs[Hn];
    hs[o] = hlast[(size_t)b * Hn + o];
    hs[o + 256] = hlast[(size_t)b * Hn + o + 256];
    __syncthreads();
    float acc = 0.0f;
#pragma unroll 8
    for (int k = 0; k < Hn; ++k)
        acc = fmaf(hs[k], Why[(size_t)k * On + o], acc);
    y[(size_t)b * On + o] = acc + bias_y[o];
}

// ---------------------------------------------------------------------------
extern "C" void kernel_launch(void* const* d_in, const int* in_sizes, int n_in,
                              void* d_out, int out_size, void* d_ws, size_t ws_size,
                              hipStream_t stream) {
    // Map inputs by size (x=33554432, Whh=262144, Wxh/Why=131072 in order,
    // bias_h=512, bias_y=256).
    const float *x = nullptr, *Wxh = nullptr, *Whh = nullptr, *Why = nullptr,
                *bias_h = nullptr, *bias_y = nullptr;
    for (int i = 0; i < n_in; ++i) {
        const float* p = (const float*)d_in[i];
        const int sz = in_sizes[i];
        if (sz == Bn * Sn * In) x = p;
        else if (sz == Hn * Hn) Whh = p;
        else if (sz == In * Hn) { if (!Wxh) Wxh = p; else Why = p; }
        else if (sz == Hn) bias_h = p;
        else if (sz == On) bias_y = p;
    }
    float* y = (float*)d_out;

    // workspace: tagged hpub (64*4*2*128 u64 = 512 KB) + hlast (128 KB).
    // NO memset: 0xAA poison decodes to negative tags -> never >= t (t>=1).
    char* ws = (char*)d_ws;
    u64* hpub = (u64*)ws;
    size_t hpub_bytes = (size_t)Bn * 4 * 2 * 128 * sizeof(u64);
    float* hlast = (float*)(ws + hpub_bytes);

    rnn_scan<<<dim3(256), dim3(256), 0, stream>>>(x, Wxh, Whh, bias_h,
                                                  hpub, hlast);
    out_gemm<<<dim3(Bn), dim3(On), 0, stream>>>(hlast, Why, bias_y, y);
}

// Round 4
// 111510.596 us; speedup vs baseline: 1.1268x; 1.1135x over previous
//
#include <hip/hip_runtime.h>
#include <stdint.h>

// Problem constants (B,S,I,H,O) = (64, 2048, 256, 512, 256), all fp32.
#define Bn 64
#define Sn 2048
#define In 256
#define Hn 512
#define On 256
#define KS 384   // front-chain length (thread A); back = Hn - KS = 128 (thread B)

// ---------------------------------------------------------------------------
// BIT-EXACT constraint (proven, absmax 0.0): per output element the
// arithmetic must be exactly
//   xacc = fma-chain_{i=0..255 asc}(xs[i], Wxh[i][j]);  xw = xacc + bias_h[j]
//   hacc = fma-chain_{k=0..511 asc}(hs[k], Whh[k][j]);  u  = xw + hacc
//   h' = xla_tanh(u);   y = fma-chain_k(h[k],Why[k][o]) + bias_y[o]
// All chains below are byte-identical to the verified versions.
//
// SYNC PROTOCOL v5. Evidence so far:
//  v0 (33.7ms): drain-barrier+release flags, 1-word broadcast spins. FETCH
//     tiny (230MB) -> spins almost never iterated; step = ~8 serial
//     agent-RTTs ~ 16.4us.
//  v2/v3/v4 (~125ms): tagged payload (no fences) BUT all three poll
//     topologies (per-lane unpaced / per-wave rtag / 1-poller 6-line
//     sleep(8)) converged to the SAME ~60us/step, FETCH ~16GB =
//     step x ~115GB/s: agent-scope (sc1) poll reads saturate the coherent
//     fabric at ~1.8G lines/s; saturation inflates RTT; publishes queue;
//     steps stretch; pollers fill the stretched step. Self-sustaining.
//     v4's offered load (6 lines/0.75us/block ~ 130GB/s) was still AT the
//     ceiling. Need 10x, not 1.5x.
// v5 = tagged payload (proven correct, keeps zero fences/drains) + poll
// offered-load crushed to ~20GB/s:
//   * ONE 64B line per batch holds all 4 slice-ready flags
//     (flags[b*16 + parity*4 + slice]) -> one poll round = ONE fabric txn
//     for all 3 remote slices (lanes 0-3 load the line, __all combines).
//   * ONE poller wave per block, s_sleep(16) (~1024cy) pacing.
//   * Readiness fans out via LDS (lready[parity]); wave1 + B-fallback spin
//     on LDS for free.
//   * Flags are a HINT only: every consumed payload word is still per-lane
//     tag-validated (paced fallback) -> correctness identical to v2-v4.
//   * Flag store is relaxed, right after the payload stores (no release
//     needed: any store-store reorder is caught by payload validation).
// Slot overwrite safety (parity double-buffer) unchanged & transitive:
// publish(t+1) <= staged all remote t <= peers published t <= peers'
// t-1 reads retired (reads pre-barrier#0, publish post-barrier#1).
// Partition unchanged (proven resident): 256 blocks = 64 batches x 4
// column-slices; 256 threads = 128 A (384 Whh regs, chain k<384) +
// 128 B (256 Wxh + 128 Whh regs, xacc + chain k>=384 + tanh + publish).
// ---------------------------------------------------------------------------
typedef unsigned long long u64;

__device__ __forceinline__ float xla_tanh(float x) {
    const float ax = __builtin_fabsf(x);
    float xc = fmaxf(-7.99881172180175781f, fminf(7.99881172180175781f, x));
    const float x2 = xc * xc;
    float p = fmaf(x2, -2.76076847742355e-16f, 2.00018790482477e-13f);
    p = fmaf(x2, p, -8.60467152213735e-11f);
    p = fmaf(x2, p, 5.12229709037114e-08f);
    p = fmaf(x2, p, 1.48572235717979e-05f);
    p = fmaf(x2, p, 6.37261928875436e-04f);
    p = fmaf(x2, p, 4.89352455891786e-03f);
    p = xc * p;
    float q = fmaf(x2, 1.19825839466702e-06f, 1.18534705686654e-04f);
    q = fmaf(x2, q, 2.26843463243900e-03f);
    q = fmaf(x2, q, 4.89352518554385e-03f);
    return ax < 0.0004f ? x : p / q;
}

__device__ __forceinline__ u64 pub_ld(const u64* p) {
    return __hip_atomic_load(p, __ATOMIC_RELAXED, __HIP_MEMORY_SCOPE_AGENT);
}
__device__ __forceinline__ void pub_st(u64* p, u64 v) {
    __hip_atomic_store(p, v, __ATOMIC_RELAXED, __HIP_MEMORY_SCOPE_AGENT);
}
__device__ __forceinline__ int tag_ld(const int* p) {
    return __hip_atomic_load(p, __ATOMIC_RELAXED, __HIP_MEMORY_SCOPE_AGENT);
}
__device__ __forceinline__ void tag_st(int* p, int v) {
    __hip_atomic_store(p, v, __ATOMIC_RELAXED, __HIP_MEMORY_SCOPE_AGENT);
}
__device__ __forceinline__ int lds_ld(const int* p) {
    return __hip_atomic_load(p, __ATOMIC_RELAXED, __HIP_MEMORY_SCOPE_WORKGROUP);
}
__device__ __forceinline__ void lds_st(int* p, int v) {
    __hip_atomic_store(p, v, __ATOMIC_RELAXED, __HIP_MEMORY_SCOPE_WORKGROUP);
}
__device__ __forceinline__ int pub_tag(u64 w) { return (int)(unsigned)(w >> 32); }
__device__ __forceinline__ float pub_val(u64 w) { return __uint_as_float((unsigned)w); }
__device__ __forceinline__ u64 pub_pack(float v, int t) {
    return ((u64)(unsigned)t << 32) | (u64)__float_as_uint(v);
}

__global__ __launch_bounds__(256, 1) void rnn_scan(const float* __restrict__ x,
                                                   const float* __restrict__ Wxh,
                                                   const float* __restrict__ Whh,
                                                   const float* __restrict__ bias_h,
                                                   u64* __restrict__ hpub,
                                                   int* __restrict__ flags,
                                                   float* __restrict__ hlast) {
    const int blk = blockIdx.x;
    const int b = blk & 63;          // batch
    const int s = blk >> 6;          // column-slice 0..3
    const int tid = threadIdx.x;
    const int c = tid & 127;         // column within slice
    const int lane = tid & 63;
    const bool isA = tid < 128;      // wave-uniform role split
    const int j = s * 128 + c;       // global column

    __shared__ float hs[2][Hn];      // double-buffered h (read t&1, write 1-(t&1))
    __shared__ float xs[2][In];      // double-buffered x row
    __shared__ float pacc[128];      // A->B chain-accumulator handoff
    __shared__ int lready[2];        // poller -> consumers: "all slices ready for t"

    // Weight registers (384 floats/thread, coalesced loads: lanes = consecutive j)
    float W0[KS];
    if (isA) {
#pragma unroll
        for (int k = 0; k < KS; ++k) W0[k] = Whh[(size_t)k * Hn + j];
    } else {
#pragma unroll
        for (int i = 0; i < In; ++i) W0[i] = Wxh[(size_t)i * Hn + j];
#pragma unroll
        for (int k = 0; k < 128; ++k) W0[In + k] = Whh[(size_t)(KS + k) * Hn + j];
    }
    const float bh = isA ? 0.f : bias_h[j];

    hs[0][tid] = 0.f;                          // h_0 = 0
    hs[0][tid + 256] = 0.f;
    xs[0][tid] = x[(size_t)b * Sn * In + tid]; // row 0 (256 threads = full row)
    if (tid < 2) lready[tid] = 0;
    __syncthreads();

    // Tagged publish slots: [batch][slice][parity][128 cols], u64 each.
    u64* const bpub = hpub + (size_t)b * 4 * 2 * 128;
    u64* const mypub = bpub + (size_t)s * 256;
    // All 4 slice flags for this batch live in ONE 64B line:
    // flags[b*16 + parity*4 + slice]
    int* const bflag = flags + b * 16;

    float hn = 0.f;

    for (int t = 0; t < Sn; ++t) {
        const int rp = t & 1;
        float xw_ = 0.f;

        if (isA) {
            if (t > 0) {
                if (tid < 64) {
                    // ---- wave0 = the block's single fabric poller ----
                    // ONE line per round: lanes 0-3 load the 4 slice flags,
                    // __all() combines wave-uniformly. s_sleep(16) pacing
                    // (~1024cy) -> ~64B / 0.8us / block offered load.
                    const int* fb = bflag + rp * 4;
                    for (;;) {
                        int f = 0;
                        if (lane < 4) f = tag_ld(fb + lane);
                        const bool ok = (lane >= 4) || (lane == s) || (f >= t);
                        if (__all(ok)) break;
                        __builtin_amdgcn_s_sleep(16);
                    }
                    if (lane == 0) lds_st(&lready[rp], t);
                } else {
                    // wave1: free LDS spin
                    while (lds_ld(&lready[rp]) < t) __builtin_amdgcn_s_sleep(1);
                }
                // ---- A staging: read payloads once, validate, LDS-write ----
                const bool na0 = (s != 0), na1 = (s != 1), na2 = (s != 2);
                const u64* p0 = bpub + 0 * 256 + rp * 128 + c;
                const u64* p1 = bpub + 1 * 256 + rp * 128 + c;
                const u64* p2 = bpub + 2 * 256 + rp * 128 + c;
                u64 v0 = 0, v1 = 0, v2 = 0;
                if (na0) v0 = pub_ld(p0);     // back-to-back: latencies overlap
                if (na1) v1 = pub_ld(p1);
                if (na2) v2 = pub_ld(p2);
                if (na0) {
                    while (pub_tag(v0) < t) { __builtin_amdgcn_s_sleep(4); v0 = pub_ld(p0); }
                    hs[rp][c] = pub_val(v0);
                }
                if (na1) {
                    while (pub_tag(v1) < t) { __builtin_amdgcn_s_sleep(4); v1 = pub_ld(p1); }
                    hs[rp][128 + c] = pub_val(v1);
                }
                if (na2) {
                    while (pub_tag(v2) < t) { __builtin_amdgcn_s_sleep(4); v2 = pub_ld(p2); }
                    hs[rp][256 + c] = pub_val(v2);
                }
            }
        } else {
            // prefetch next x row (2 elems/thread), issued first to hide latency
            float xn0 = 0.f, xn1 = 0.f;
            if (t + 1 < Sn) {
                xn0 = x[((size_t)b * Sn + t + 1) * In + c];
                xn1 = x[((size_t)b * Sn + t + 1) * In + 128 + c];
            }
            // speculative slice-3 payload read issued BEFORE xacc: the 1024cy
            // chain hides the RTT; if stale, fall back to the free LDS flag
            const bool need3 = (t > 0) && (s != 3);
            const u64* p3 = bpub + 3 * 256 + rp * 128 + c;
            u64 v3 = 0;
            if (need3) v3 = pub_ld(p3);

            // xacc: i = 0..255, ascending (exact verified order)
            float xa = 0.f;
            const float4* x4 = (const float4*)&xs[rp][0];
#pragma unroll
            for (int q = 0; q < In / 4; ++q) {
                float4 xv = x4[q];
                xa = fmaf(xv.x, W0[4 * q + 0], xa);
                xa = fmaf(xv.y, W0[4 * q + 1], xa);
                xa = fmaf(xv.z, W0[4 * q + 2], xa);
                xa = fmaf(xv.w, W0[4 * q + 3], xa);
            }
            xw_ = xa + bh;

            if (need3) {
                if (pub_tag(v3) < t) {
                    // speculation failed: wait on poller's LDS flag (free),
                    // then one fresh read + paced per-lane validation
                    while (lds_ld(&lready[rp]) < t) __builtin_amdgcn_s_sleep(1);
                    v3 = pub_ld(p3);
                    while (pub_tag(v3) < t) { __builtin_amdgcn_s_sleep(4); v3 = pub_ld(p3); }
                }
                hs[rp][KS + c] = pub_val(v3);   // slice 3 (B's chain range)
            }
            if (t + 1 < Sn) {
                xs[1 - rp][c] = xn0;
                xs[1 - rp][128 + c] = xn1;
            }
        }
        __syncthreads();   // #0: hs[rp] complete (remote staged, local from t-1)

        if (isA) {
            // hacc prefix: k = 0..383, ascending, single accumulator (exact order)
            float acc = 0.f;
            const float4* h4 = (const float4*)&hs[rp][0];
#pragma unroll
            for (int q = 0; q < KS / 4; ++q) {
                float4 hv = h4[q];   // broadcast ds_read_b128
                acc = fmaf(hv.x, W0[4 * q + 0], acc);
                acc = fmaf(hv.y, W0[4 * q + 1], acc);
                acc = fmaf(hv.z, W0[4 * q + 2], acc);
                acc = fmaf(hv.w, W0[4 * q + 3], acc);
            }
            pacc[c] = acc;
        }
        __syncthreads();   // #1: pacc ready

        if (!isA) {
            // hacc suffix: k = 384..511, continuing the SAME chain
            float acc = pacc[c];
            const float4* h4 = (const float4*)&hs[rp][KS];
#pragma unroll
            for (int q = 0; q < 32; ++q) {
                float4 hv = h4[q];
                acc = fmaf(hv.x, W0[In + 4 * q + 0], acc);
                acc = fmaf(hv.y, W0[In + 4 * q + 1], acc);
                acc = fmaf(hv.z, W0[In + 4 * q + 2], acc);
                acc = fmaf(hv.w, W0[In + 4 * q + 3], acc);
            }
            const float u = xw_ + acc;        // exact association
            hn = xla_tanh(u);
            hs[1 - rp][j] = hn;               // local slice for step t+1
            if (t + 1 < Sn) {
                // tagged payload publish: tag travels WITH the value
                pub_st(mypub + (size_t)(1 - rp) * 128 + c, pub_pack(hn, t + 1));
                // flag hint: relaxed, after the payload stores of THIS wave;
                // any reorder / wave-3 straggler is caught by per-lane
                // payload validation at the consumer
                if (tid == 128) tag_st(bflag + (1 - rp) * 4 + s, t + 1);
            }
        }
        // no third barrier: LDS hazards for t+1 are covered by #0/#1
    }

    if (!isA) hlast[(size_t)b * Hn + j] = hn;
}

// ---------------------------------------------------------------------------
// y[b][o] = fma-chain_k(h_last[b][k]*Why[k][o]) + bias_y[o]  (unchanged, exact)
// ---------------------------------------------------------------------------
__global__ __launch_bounds__(256) void out_gemm(const float* __restrict__ hlast,
                                                const float* __restrict__ Why,
                                                const float* __restrict__ bias_y,
                                                float* __restrict__ y) {
    const int b = blockIdx.x, o = threadIdx.x;
    __shared__ float hs[Hn];
    hs[o] = hlast[(size_t)b * Hn + o];
    hs[o + 256] = hlast[(size_t)b * Hn + o + 256];
    __syncthreads();
    float acc = 0.0f;
#pragma unroll 8
    for (int k = 0; k < Hn; ++k)
        acc = fmaf(hs[k], Why[(size_t)k * On + o], acc);
    y[(size_t)b * On + o] = acc + bias_y[o];
}

// ---------------------------------------------------------------------------
extern "C" void kernel_launch(void* const* d_in, const int* in_sizes, int n_in,
                              void* d_out, int out_size, void* d_ws, size_t ws_size,
                              hipStream_t stream) {
    // Map inputs by size (x=33554432, Whh=262144, Wxh/Why=131072 in order,
    // bias_h=512, bias_y=256).
    const float *x = nullptr, *Wxh = nullptr, *Whh = nullptr, *Why = nullptr,
                *bias_h = nullptr, *bias_y = nullptr;
    for (int i = 0; i < n_in; ++i) {
        const float* p = (const float*)d_in[i];
        const int sz = in_sizes[i];
        if (sz == Bn * Sn * In) x = p;
        else if (sz == Hn * Hn) Whh = p;
        else if (sz == In * Hn) { if (!Wxh) Wxh = p; else Why = p; }
        else if (sz == Hn) bias_h = p;
        else if (sz == On) bias_y = p;
    }
    float* y = (float*)d_out;

    // workspace: tagged hpub (64*4*2*128 u64 = 512 KB) + flags (4 KB, one
    // 64B line per batch) + hlast (128 KB). NO memset: 0xAA poison decodes
    // to negative tags/flags -> never >= t for t >= 1.
    char* ws = (char*)d_ws;
    u64* hpub = (u64*)ws;
    size_t hpub_bytes = (size_t)Bn * 4 * 2 * 128 * sizeof(u64);
    int* flags = (int*)(ws + hpub_bytes);
    size_t flag_bytes = (size_t)Bn * 16 * sizeof(int);
    float* hlast = (float*)(ws + hpub_bytes + flag_bytes);

    rnn_scan<<<dim3(256), dim3(256), 0, stream>>>(x, Wxh, Whh, bias_h,
                                                  hpub, flags, hlast);
    out_gemm<<<dim3(Bn), dim3(On), 0, stream>>>(hlast, Why, bias_y, y);
}